// Round 1
// baseline (651.290 us; speedup 1.0000x reference)
//
#include <hip/hip_runtime.h>

constexpr int T_STEPS = 32;
constexpr int BATCH   = 32;
constexpr int DG      = 256;
constexpr int DH      = 512;
constexpr int NHIST   = 31;
constexpr float LAMBDA_ = 0.95f;
constexpr float ETA_    = 0.5f;
constexpr float EPS_    = 1e-5f;

// Kernel 1: ZG[tb][i] = b_h[i] + sum_j z[tb][j] * W_g[i][j]
// 256 blocks x 512 threads; each block handles 4 consecutive (t,b) pairs,
// amortizing the W_g row reads 4x. Wave-per-row, lanes across the 256 cols.
__global__ __launch_bounds__(512) void zg_kernel(
    const float* __restrict__ z, const float* __restrict__ Wg,
    const float* __restrict__ bh, float* __restrict__ ZG) {
  const int lane = threadIdx.x & 63;
  const int wave = threadIdx.x >> 6;   // 0..7
  const int tb0  = blockIdx.x * 4;
  float4 zv[4];
#pragma unroll
  for (int p = 0; p < 4; ++p)
    zv[p] = *reinterpret_cast<const float4*>(z + (size_t)(tb0 + p) * DG + lane * 4);
  for (int k = 0; k < 64; ++k) {
    const int r = wave * 64 + k;
    const float4 wv = *reinterpret_cast<const float4*>(Wg + (size_t)r * DG + lane * 4);
    float a0 = zv[0].x*wv.x + zv[0].y*wv.y + zv[0].z*wv.z + zv[0].w*wv.w;
    float a1 = zv[1].x*wv.x + zv[1].y*wv.y + zv[1].z*wv.z + zv[1].w*wv.w;
    float a2 = zv[2].x*wv.x + zv[2].y*wv.y + zv[2].z*wv.z + zv[2].w*wv.w;
    float a3 = zv[3].x*wv.x + zv[3].y*wv.y + zv[3].z*wv.z + zv[3].w*wv.w;
#pragma unroll
    for (int off = 32; off; off >>= 1) {
      a0 += __shfl_xor(a0, off, 64);
      a1 += __shfl_xor(a1, off, 64);
      a2 += __shfl_xor(a2, off, 64);
      a3 += __shfl_xor(a3, off, 64);
    }
    if (lane == 0) {
      const float bb = bh[r];
      ZG[(size_t)(tb0 + 0) * DH + r] = a0 + bb;
      ZG[(size_t)(tb0 + 1) * DH + r] = a1 + bb;
      ZG[(size_t)(tb0 + 2) * DH + r] = a2 + bb;
      ZG[(size_t)(tb0 + 3) * DH + r] = a3 + bb;
    }
  }
}

// Kernel 2: the serial recurrence. One block per batch (32 blocks x 1024 thr).
// Fast-weight A kept implicitly as low-rank history in LDS:
//   A·h = ETA * sum_{s<t} LAMBDA^(t-1-s) (h_s · h) h_s
__global__ __launch_bounds__(1024) void rnn_kernel(
    const float* __restrict__ Wh, const float* __restrict__ ZG,
    const float* __restrict__ g, const float* __restrict__ be,
    float* __restrict__ out) {
  // hist padded 31->40 rows: total LDS ~86 KB forces 1 block/CU (no 2-block packing)
  __shared__ float hist[40][DH];
  __shared__ float h_s[DH];
  __shared__ float hb_s[DH];
  __shared__ float cc[NHIST];
  __shared__ float redA[8], redB[8];
  __shared__ float lam_pow[NHIST];
  __shared__ float stat[2];

  const int tid  = threadIdx.x;
  const int lane = tid & 63;
  const int wave = tid >> 6;          // 0..15
  const int b    = blockIdx.x;

  if (tid == 0) {
    float p = 1.f;
    for (int k = 0; k < NHIST; ++k) { lam_pow[k] = p; p *= LAMBDA_; }
  }
  if (tid < DH) h_s[tid] = 0.f;
  float g_i = 0.f, be_i = 0.f;
  if (tid < DH) { g_i = g[tid]; be_i = be[tid]; }
  __syncthreads();

  // block LayerNorm + relu over hb values held per-thread (tid<DH); writes h_s
  auto ln_relu = [&](float x) {
    float s1 = (tid < DH) ? x : 0.f;
    float s2 = (tid < DH) ? x * x : 0.f;
#pragma unroll
    for (int off = 32; off; off >>= 1) {
      s1 += __shfl_xor(s1, off, 64);
      s2 += __shfl_xor(s2, off, 64);
    }
    if (tid < DH && lane == 0) { redA[wave] = s1; redB[wave] = s2; }
    __syncthreads();
    if (tid == 0) {
      float a = 0.f, q = 0.f;
#pragma unroll
      for (int w = 0; w < 8; ++w) { a += redA[w]; q += redB[w]; }
      const float mu  = a * (1.f / DH);
      const float var = q * (1.f / DH) - mu * mu;
      stat[0] = mu;
      stat[1] = rsqrtf(var + EPS_);
    }
    __syncthreads();
    if (tid < DH) {
      const float v = (x - stat[0]) * stat[1] * g_i + be_i;
      h_s[tid] = v > 0.f ? v : 0.f;
    }
    __syncthreads();
  };

  for (int t = 0; t < T_STEPS; ++t) {
    const float* zg = ZG + ((size_t)t * BATCH + b) * DH;

    // Phase 1: hb = h @ Wh^T + zg   (wave-per-row, lanes across 512 cols)
    if (t == 0) {
      if (tid < DH) hb_s[tid] = zg[tid];   // h == 0
    } else {
      const float4 h0 = *reinterpret_cast<const float4*>(&h_s[lane * 4]);
      const float4 h1 = *reinterpret_cast<const float4*>(&h_s[256 + lane * 4]);
#pragma unroll 4
      for (int k = 0; k < 32; ++k) {
        const int r = wave * 32 + k;
        const float* wr = Wh + (size_t)r * DH;
        const float4 w0 = *reinterpret_cast<const float4*>(wr + lane * 4);
        const float4 w1 = *reinterpret_cast<const float4*>(wr + 256 + lane * 4);
        float acc = h0.x*w0.x + h0.y*w0.y + h0.z*w0.z + h0.w*w0.w
                  + h1.x*w1.x + h1.y*w1.y + h1.z*w1.z + h1.w*w1.w;
#pragma unroll
        for (int off = 32; off; off >>= 1) acc += __shfl_xor(acc, off, 64);
        if (lane == 0) hb_s[r] = acc + zg[r];
      }
    }
    __syncthreads();

    // Phase 2: h = relu(LN(hb))
    const float xb = (tid < DH) ? hb_s[tid] : 0.f;
    ln_relu(xb);

    // Phase 3: S_LOOP=2 fast-weight reads (skip at t=0: A==0 -> h unchanged)
    if (t > 0) {
      for (int s = 0; s < 2; ++s) {
        // dots d_sp = h_sp . h ; coefficient cc[sp] = ETA*lambda^(t-1-sp)*d_sp
        const float4 hc0 = *reinterpret_cast<const float4*>(&h_s[lane * 4]);
        const float4 hc1 = *reinterpret_cast<const float4*>(&h_s[256 + lane * 4]);
        for (int sp = wave; sp < t; sp += 16) {
          const float* hr = hist[sp];
          const float4 a0 = *reinterpret_cast<const float4*>(&hr[lane * 4]);
          const float4 a1 = *reinterpret_cast<const float4*>(&hr[256 + lane * 4]);
          float d = hc0.x*a0.x + hc0.y*a0.y + hc0.z*a0.z + hc0.w*a0.w
                  + hc1.x*a1.x + hc1.y*a1.y + hc1.z*a1.z + hc1.w*a1.w;
#pragma unroll
          for (int off = 32; off; off >>= 1) d += __shfl_xor(d, off, 64);
          if (lane == 0) cc[sp] = ETA_ * lam_pow[t - 1 - sp] * d;
        }
        __syncthreads();
        // Ah[i] = sum_sp cc[sp]*hist[sp][i]; h = relu(LN(hb + Ah))
        float x2 = xb;
        if (tid < DH) {
          float ah = 0.f;
          for (int sp = 0; sp < t; ++sp) ah += cc[sp] * hist[sp][tid];
          x2 = xb + ah;
        }
        ln_relu(x2);
      }
    }

    // Phase 4: Hebbian write == append h to history (steps 0..T-2 only)
    if (t < T_STEPS - 1) {
      if (tid < DH) hist[t][tid] = h_s[tid];
      __syncthreads();
    }
  }

  if (tid < DH) out[(size_t)b * DH + tid] = h_s[tid];
}

extern "C" void kernel_launch(void* const* d_in, const int* in_sizes, int n_in,
                              void* d_out, int out_size, void* d_ws, size_t ws_size,
                              hipStream_t stream) {
  const float* z     = (const float*)d_in[0];  // [T,B,DG]
  const float* W_h   = (const float*)d_in[1];  // [DH,DH]
  const float* W_g   = (const float*)d_in[2];  // [DH,DG]
  const float* b_h   = (const float*)d_in[3];  // [DH]
  const float* gamma = (const float*)d_in[4];  // [DH]
  const float* beta  = (const float*)d_in[5];  // [DH]
  float* out = (float*)d_out;                  // [B,DH]
  float* ZG  = (float*)d_ws;                   // [T*B,DH] = 2 MB scratch

  zg_kernel<<<dim3(T_STEPS * BATCH / 4), dim3(512), 0, stream>>>(z, W_g, b_h, ZG);
  rnn_kernel<<<dim3(BATCH), dim3(1024), 0, stream>>>(W_h, ZG, gamma, beta, out);
}

// Round 2
// 561.986 us; speedup vs baseline: 1.1589x; 1.1589x over previous
//
#include <hip/hip_runtime.h>

constexpr int T_STEPS = 32;
constexpr int BATCH   = 32;
constexpr int DG      = 256;
constexpr int DH      = 512;
constexpr int NHIST   = 31;
constexpr float LAMBDA_ = 0.95f;
constexpr float ETA_    = 0.5f;
constexpr float EPS_    = 1e-5f;

// Kernel 0: convert W_h fp32 -> bf16 (RNE) into workspace.
__global__ __launch_bounds__(256) void prep_kernel(const float* __restrict__ Wh,
                                                   ushort* __restrict__ Whb) {
  const int idx = (blockIdx.x * 256 + threadIdx.x) * 4;
  const float4 v = *reinterpret_cast<const float4*>(Wh + idx);
  auto cvt = [](float f) -> ushort {
    uint u = __float_as_uint(f);
    return (ushort)((u + 0x7FFFu + ((u >> 16) & 1u)) >> 16);
  };
  ushort4 o;
  o.x = cvt(v.x); o.y = cvt(v.y); o.z = cvt(v.z); o.w = cvt(v.w);
  *reinterpret_cast<ushort4*>(Whb + idx) = o;
}

// Kernel 1: ZG[tb][i] = b_h[i] + sum_j z[tb][j] * W_g[i][j]
__global__ __launch_bounds__(512) void zg_kernel(
    const float* __restrict__ z, const float* __restrict__ Wg,
    const float* __restrict__ bh, float* __restrict__ ZG) {
  const int lane = threadIdx.x & 63;
  const int wave = threadIdx.x >> 6;   // 0..7
  const int tb0  = blockIdx.x * 4;
  float4 zv[4];
#pragma unroll
  for (int p = 0; p < 4; ++p)
    zv[p] = *reinterpret_cast<const float4*>(z + (size_t)(tb0 + p) * DG + lane * 4);
  for (int k = 0; k < 64; ++k) {
    const int r = wave * 64 + k;
    const float4 wv = *reinterpret_cast<const float4*>(Wg + (size_t)r * DG + lane * 4);
    float a0 = zv[0].x*wv.x + zv[0].y*wv.y + zv[0].z*wv.z + zv[0].w*wv.w;
    float a1 = zv[1].x*wv.x + zv[1].y*wv.y + zv[1].z*wv.z + zv[1].w*wv.w;
    float a2 = zv[2].x*wv.x + zv[2].y*wv.y + zv[2].z*wv.z + zv[2].w*wv.w;
    float a3 = zv[3].x*wv.x + zv[3].y*wv.y + zv[3].z*wv.z + zv[3].w*wv.w;
#pragma unroll
    for (int off = 32; off; off >>= 1) {
      a0 += __shfl_xor(a0, off, 64);
      a1 += __shfl_xor(a1, off, 64);
      a2 += __shfl_xor(a2, off, 64);
      a3 += __shfl_xor(a3, off, 64);
    }
    if (lane == 0) {
      const float bb = bh[r];
      ZG[(size_t)(tb0 + 0) * DH + r] = a0 + bb;
      ZG[(size_t)(tb0 + 1) * DH + r] = a1 + bb;
      ZG[(size_t)(tb0 + 2) * DH + r] = a2 + bb;
      ZG[(size_t)(tb0 + 3) * DH + r] = a3 + bb;
    }
  }
}

// Kernel 2: serial recurrence, one block per batch.
// A kept implicitly low-rank: A.h = ETA * sum_{s<t} LAMBDA^(t-1-s) (h_s.h) h_s
__global__ __launch_bounds__(1024) void rnn_kernel(
    const ushort* __restrict__ Whb, const float* __restrict__ ZG,
    const float* __restrict__ g, const float* __restrict__ be,
    float* __restrict__ out) {
  __shared__ float hist[NHIST][DH];   // 62 KB
  __shared__ float h_s[DH];
  __shared__ float hb_s[DH];
  __shared__ float cc[NHIST];
  __shared__ float redA[2], redB[2];
  __shared__ float lam_pow[NHIST];

  const int tid  = threadIdx.x;
  const int lane = tid & 63;
  const int wave = tid >> 6;          // 0..15
  const int b    = blockIdx.x;
  const bool owner = (tid < 128);     // waves 0,1: 4 channels each via float4
  const int i4 = tid * 4;

  if (tid == 0) {
    float p = 1.f;
    for (int k = 0; k < NHIST; ++k) { lam_pow[k] = p; p *= LAMBDA_; }
  }
  if (tid < DH) h_s[tid] = 0.f;
  float4 g4 = {0,0,0,0}, be4 = {0,0,0,0};
  if (owner) {
    g4  = *reinterpret_cast<const float4*>(g  + i4);
    be4 = *reinterpret_cast<const float4*>(be + i4);
  }
  __syncthreads();

  // LayerNorm+ReLU on owner-held float4; 2 block syncs; returns h4, writes h_s.
  auto ln4 = [&](float4 x) -> float4 {
    if (wave < 2) {
      float s1 = x.x + x.y + x.z + x.w;
      float s2 = x.x*x.x + x.y*x.y + x.z*x.z + x.w*x.w;
#pragma unroll
      for (int off = 32; off; off >>= 1) {
        s1 += __shfl_xor(s1, off, 64);
        s2 += __shfl_xor(s2, off, 64);
      }
      if (lane == 0) { redA[wave] = s1; redB[wave] = s2; }
    }
    __syncthreads();
    float4 r = {0,0,0,0};
    if (owner) {
      const float a = redA[0] + redA[1];
      const float q = redB[0] + redB[1];
      const float mu = a * (1.f / DH);
      const float rs = rsqrtf(q * (1.f / DH) - mu * mu + EPS_);
      r.x = fmaxf((x.x - mu) * rs * g4.x + be4.x, 0.f);
      r.y = fmaxf((x.y - mu) * rs * g4.y + be4.y, 0.f);
      r.z = fmaxf((x.z - mu) * rs * g4.z + be4.z, 0.f);
      r.w = fmaxf((x.w - mu) * rs * g4.w + be4.w, 0.f);
      *reinterpret_cast<float4*>(h_s + i4) = r;
    }
    __syncthreads();
    return r;
  };

  float4 h4 = {0,0,0,0};
  for (int t = 0; t < T_STEPS; ++t) {
    const float* zg = ZG + ((size_t)t * BATCH + b) * DH;
    float4 hb4 = {0,0,0,0};

    if (t == 0) {
      if (owner) hb4 = *reinterpret_cast<const float4*>(zg + i4);   // h==0
    } else {
      // Phase 1: hb = h @ Wh^T  (wave-per-row, bf16 weights, one uint4/lane/row)
      float hl[8];
      {
        const float4 a = *reinterpret_cast<const float4*>(h_s + lane * 8);
        const float4 c = *reinterpret_cast<const float4*>(h_s + lane * 8 + 4);
        hl[0]=a.x; hl[1]=a.y; hl[2]=a.z; hl[3]=a.w;
        hl[4]=c.x; hl[5]=c.y; hl[6]=c.z; hl[7]=c.w;
      }
#pragma unroll 4
      for (int k = 0; k < 32; ++k) {
        const int r = wave * 32 + k;
        const uint4 wv = *reinterpret_cast<const uint4*>(Whb + (size_t)r * DH + lane * 8);
        float acc;
        acc =      __uint_as_float(wv.x << 16)          * hl[0];
        acc = fmaf(__uint_as_float(wv.x & 0xFFFF0000u), hl[1], acc);
        acc = fmaf(__uint_as_float(wv.y << 16),         hl[2], acc);
        acc = fmaf(__uint_as_float(wv.y & 0xFFFF0000u), hl[3], acc);
        acc = fmaf(__uint_as_float(wv.z << 16),         hl[4], acc);
        acc = fmaf(__uint_as_float(wv.z & 0xFFFF0000u), hl[5], acc);
        acc = fmaf(__uint_as_float(wv.w << 16),         hl[6], acc);
        acc = fmaf(__uint_as_float(wv.w & 0xFFFF0000u), hl[7], acc);
#pragma unroll
        for (int off = 32; off; off >>= 1) acc += __shfl_xor(acc, off, 64);
        if (lane == 0) hb_s[r] = acc;
      }
      __syncthreads();
      if (owner) {
        const float4 m  = *reinterpret_cast<const float4*>(hb_s + i4);
        const float4 z4 = *reinterpret_cast<const float4*>(zg + i4);
        hb4 = make_float4(m.x + z4.x, m.y + z4.y, m.z + z4.z, m.w + z4.w);
      }
    }

    // Phase 2: h = relu(LN(hb))
    h4 = ln4(hb4);

    // Phase 3: S_LOOP=2 fast-weight reads (A==0 at t=0 -> skip)
    if (t > 0) {
      for (int s = 0; s < 2; ++s) {
        // dots: cc[sp] = ETA*lambda^(t-1-sp) * (hist[sp] . h)
        const float4 c0 = *reinterpret_cast<const float4*>(h_s + lane * 8);
        const float4 c1 = *reinterpret_cast<const float4*>(h_s + lane * 8 + 4);
        for (int sp = wave; sp < t; sp += 16) {
          const float* hr = hist[sp];
          const float4 a0 = *reinterpret_cast<const float4*>(hr + lane * 8);
          const float4 a1 = *reinterpret_cast<const float4*>(hr + lane * 8 + 4);
          float d = c0.x*a0.x + c0.y*a0.y + c0.z*a0.z + c0.w*a0.w
                  + c1.x*a1.x + c1.y*a1.y + c1.z*a1.z + c1.w*a1.w;
#pragma unroll
          for (int off = 32; off; off >>= 1) d += __shfl_xor(d, off, 64);
          if (lane == 0) cc[sp] = ETA_ * lam_pow[t - 1 - sp] * d;
        }
        __syncthreads();
        // Ah (owners, float4 over LDS) ; h = relu(LN(hb + Ah))
        float4 x = hb4;
        if (owner) {
          float4 ah = {0,0,0,0};
          for (int sp = 0; sp < t; ++sp) {
            const float c = cc[sp];
            const float4 hv = *reinterpret_cast<const float4*>(&hist[sp][i4]);
            ah.x = fmaf(c, hv.x, ah.x);
            ah.y = fmaf(c, hv.y, ah.y);
            ah.z = fmaf(c, hv.z, ah.z);
            ah.w = fmaf(c, hv.w, ah.w);
          }
          x = make_float4(hb4.x + ah.x, hb4.y + ah.y, hb4.z + ah.z, hb4.w + ah.w);
        }
        h4 = ln4(x);
      }
    }

    // Phase 4: append h to history (from registers; next step's Phase-1 sync
    // orders this write before any subsequent hist[t] read)
    if (t < T_STEPS - 1 && owner)
      *reinterpret_cast<float4*>(&hist[t][i4]) = h4;
  }

  if (owner) *reinterpret_cast<float4*>(out + (size_t)b * DH + i4) = h4;
}

extern "C" void kernel_launch(void* const* d_in, const int* in_sizes, int n_in,
                              void* d_out, int out_size, void* d_ws, size_t ws_size,
                              hipStream_t stream) {
  const float* z     = (const float*)d_in[0];  // [T,B,DG]
  const float* W_h   = (const float*)d_in[1];  // [DH,DH]
  const float* W_g   = (const float*)d_in[2];  // [DH,DG]
  const float* b_h   = (const float*)d_in[3];  // [DH]
  const float* gamma = (const float*)d_in[4];  // [DH]
  const float* beta  = (const float*)d_in[5];  // [DH]
  float* out = (float*)d_out;                  // [B,DH]

  float*  ZG  = (float*)d_ws;                          // 2 MB
  ushort* Whb = (ushort*)((char*)d_ws + (size_t)T_STEPS * BATCH * DH * 4); // 512 KB

  prep_kernel<<<dim3(DH * DH / 1024), dim3(256), 0, stream>>>(W_h, Whb);
  zg_kernel<<<dim3(T_STEPS * BATCH / 4), dim3(512), 0, stream>>>(z, W_g, b_h, ZG);
  rnn_kernel<<<dim3(BATCH), dim3(1024), 0, stream>>>(Whb, ZG, gamma, beta, out);
}

// Round 3
// 340.418 us; speedup vs baseline: 1.9132x; 1.6509x over previous
//
#include <hip/hip_runtime.h>

constexpr int T_STEPS = 32;
constexpr int BATCH   = 32;
constexpr int DG      = 256;
constexpr int DH      = 512;
constexpr int NHIST   = 31;
constexpr float LAMBDA_ = 0.95f;
constexpr float ETA_    = 0.5f;
constexpr float EPS_    = 1e-5f;

// aux kernel: blocks 0..255 compute ZG = z @ Wg^T + bh ; blocks 256..319 pack
// W_h fp32 -> bf16 in transposed tile layout Wp[(k8h)*512 + r] (uint4 = 8 bf16
// of W[r][k8h*8 .. +8)) so the rnn matvec loads are lane-coalesced.
__global__ __launch_bounds__(512) void aux_kernel(
    const float* __restrict__ z, const float* __restrict__ Wg,
    const float* __restrict__ bh, float* __restrict__ ZG,
    const float* __restrict__ Wh, uint4* __restrict__ Wp) {
  const int tid = threadIdx.x;
  if (blockIdx.x < 256) {
    const int lane = tid & 63;
    const int wave = tid >> 6;   // 0..7
    const int tb0  = blockIdx.x * 4;
    float4 zv[4];
#pragma unroll
    for (int p = 0; p < 4; ++p)
      zv[p] = *reinterpret_cast<const float4*>(z + (size_t)(tb0 + p) * DG + lane * 4);
    for (int k = 0; k < 64; ++k) {
      const int r = wave * 64 + k;
      const float4 wv = *reinterpret_cast<const float4*>(Wg + (size_t)r * DG + lane * 4);
      float a0 = zv[0].x*wv.x + zv[0].y*wv.y + zv[0].z*wv.z + zv[0].w*wv.w;
      float a1 = zv[1].x*wv.x + zv[1].y*wv.y + zv[1].z*wv.z + zv[1].w*wv.w;
      float a2 = zv[2].x*wv.x + zv[2].y*wv.y + zv[2].z*wv.z + zv[2].w*wv.w;
      float a3 = zv[3].x*wv.x + zv[3].y*wv.y + zv[3].z*wv.z + zv[3].w*wv.w;
#pragma unroll
      for (int off = 32; off; off >>= 1) {
        a0 += __shfl_xor(a0, off, 64);
        a1 += __shfl_xor(a1, off, 64);
        a2 += __shfl_xor(a2, off, 64);
        a3 += __shfl_xor(a3, off, 64);
      }
      if (lane == 0) {
        const float bb = bh[r];
        ZG[(size_t)(tb0 + 0) * DH + r] = a0 + bb;
        ZG[(size_t)(tb0 + 1) * DH + r] = a1 + bb;
        ZG[(size_t)(tb0 + 2) * DH + r] = a2 + bb;
        ZG[(size_t)(tb0 + 3) * DH + r] = a3 + bb;
      }
    }
  } else {
    // pack: v in [0, 512*64): r = v>>6 row, k8h = v&63 (8-col group)
    const int v = (blockIdx.x - 256) * 512 + tid;
    const int r = v >> 6;
    const int k8h = v & 63;
    const float4 a = *reinterpret_cast<const float4*>(Wh + (size_t)r * DH + k8h * 8);
    const float4 b = *reinterpret_cast<const float4*>(Wh + (size_t)r * DH + k8h * 8 + 4);
    auto cvt = [](float f) -> uint {
      uint u = __float_as_uint(f);
      return (u + 0x7FFFu + ((u >> 16) & 1u)) >> 16;
    };
    uint4 o;
    o.x = cvt(a.x) | (cvt(a.y) << 16);
    o.y = cvt(a.z) | (cvt(a.w) << 16);
    o.z = cvt(b.x) | (cvt(b.y) << 16);
    o.w = cvt(b.z) | (cvt(b.w) << 16);
    Wp[(size_t)k8h * DH + r] = o;
  }
}

// Serial recurrence: one block per batch. 1024 threads = 512 row-owners x 2
// K-halves. hb[r] accumulated in a register per thread: coalesced Wp loads,
// wave-uniform (broadcast) LDS reads of h, no shuffles in the matvec.
// A kept implicitly low-rank: A.h = ETA * sum_{s<t} LAMBDA^(t-1-s) (h_s.h) h_s
__global__ __launch_bounds__(1024) void rnn_kernel(
    const uint4* __restrict__ Wp, const float* __restrict__ ZG,
    const float* __restrict__ g, const float* __restrict__ be,
    float* __restrict__ out) {
  __shared__ alignas(16) float hist[40][DH];   // 80 KB (padded: 1 block/CU)
  __shared__ alignas(16) float4 h4_s[DH / 4];
  __shared__ float part[DH];
  __shared__ float cc[NHIST];
  __shared__ float red1[16], red2[16];
  __shared__ float lam_pow[NHIST];

  float* h_s = reinterpret_cast<float*>(h4_s);
  const int tid  = threadIdx.x;
  const int lane = tid & 63;
  const int wave = tid >> 6;       // 0..15
  const int r    = tid & 511;      // owned output row
  const int kh   = tid >> 9;       // 0/1: K-half
  const int b    = blockIdx.x;
  const bool own = (kh == 0);

  if (tid == 0) {
    float p = 1.f;
    for (int k = 0; k < NHIST; ++k) { lam_pow[k] = p; p *= LAMBDA_; }
  }
  float g_r = 0.f, be_r = 0.f;
  if (own) { g_r = g[r]; be_r = be[r]; }

  // LayerNorm+ReLU over the 512 owner-held scalars; 2 barriers; writes h_s.
  auto ln = [&](float x) -> float {
    float s1 = own ? x : 0.f;
    float s2 = own ? x * x : 0.f;
#pragma unroll
    for (int off = 32; off; off >>= 1) {
      s1 += __shfl_xor(s1, off, 64);
      s2 += __shfl_xor(s2, off, 64);
    }
    if (lane == 0) { red1[wave] = s1; red2[wave] = s2; }
    __syncthreads();
    float a = 0.f, q = 0.f;
#pragma unroll
    for (int w2 = 0; w2 < 16; ++w2) { a += red1[w2]; q += red2[w2]; }
    const float mu = a * (1.f / DH);
    const float rs = rsqrtf(q * (1.f / DH) - mu * mu + EPS_);
    float hv = 0.f;
    if (own) {
      hv = fmaxf((x - mu) * rs * g_r + be_r, 0.f);
      h_s[r] = hv;
    }
    __syncthreads();
    return hv;
  };

  float hv = 0.f;
  for (int t = 0; t < T_STEPS; ++t) {
    const float* zg = ZG + ((size_t)t * BATCH + b) * DH;
    float xb;

    if (t == 0) {
      xb = own ? zg[r] : 0.f;
    } else {
      // Phase 1: hb[r] += sum over this K-half. Coalesced Wp loads (lanes are
      // consecutive r), uniform h4_s reads (broadcast).
      const uint4* wp = Wp + (size_t)(kh * 32) * DH + r;
      const float4* hh = h4_s + kh * 64;
      float acc = 0.f;
#pragma unroll 4
      for (int k8 = 0; k8 < 32; ++k8) {
        const uint4 wv = wp[(size_t)k8 * DH];
        const float4 ha = hh[k8 * 2];
        const float4 hb = hh[k8 * 2 + 1];
        acc = fmaf(__uint_as_float(wv.x << 16),           ha.x, acc);
        acc = fmaf(__uint_as_float(wv.x & 0xFFFF0000u),   ha.y, acc);
        acc = fmaf(__uint_as_float(wv.y << 16),           ha.z, acc);
        acc = fmaf(__uint_as_float(wv.y & 0xFFFF0000u),   ha.w, acc);
        acc = fmaf(__uint_as_float(wv.z << 16),           hb.x, acc);
        acc = fmaf(__uint_as_float(wv.z & 0xFFFF0000u),   hb.y, acc);
        acc = fmaf(__uint_as_float(wv.w << 16),           hb.z, acc);
        acc = fmaf(__uint_as_float(wv.w & 0xFFFF0000u),   hb.w, acc);
      }
      if (!own) part[r] = acc;
      __syncthreads();                                   // B1
      xb = own ? (acc + part[r] + zg[r]) : 0.f;
    }

    // Phase 2: h = relu(LN(hb))
    hv = ln(xb);                                          // B2,B3

    // Phase 3: S_LOOP=2 fast-weight reads (A==0 at t=0 -> skip)
    if (t > 0) {
      for (int s = 0; s < 2; ++s) {
        // cc[sp] = ETA*lambda^(t-1-sp) * (hist[sp] . h); wave handles sp, sp+16
        const float4 c0 = *reinterpret_cast<const float4*>(h_s + lane * 8);
        const float4 c1 = *reinterpret_cast<const float4*>(h_s + lane * 8 + 4);
        for (int sp = wave; sp < t; sp += 16) {
          const float* hr = hist[sp];
          const float4 a0 = *reinterpret_cast<const float4*>(hr + lane * 8);
          const float4 a1 = *reinterpret_cast<const float4*>(hr + lane * 8 + 4);
          float d = c0.x*a0.x + c0.y*a0.y + c0.z*a0.z + c0.w*a0.w
                  + c1.x*a1.x + c1.y*a1.y + c1.z*a1.z + c1.w*a1.w;
#pragma unroll
          for (int off = 32; off; off >>= 1) d += __shfl_xor(d, off, 64);
          if (lane == 0) cc[sp] = ETA_ * lam_pow[t - 1 - sp] * d;
        }
        __syncthreads();                                  // B4
        float x2 = xb;
        if (own) {
          float ah = 0.f;
          for (int sp = 0; sp < t; ++sp) ah = fmaf(cc[sp], hist[sp][r], ah);
          x2 = xb + ah;
        }
        hv = ln(x2);                                      // B5,B6
      }
    }

    // Phase 4: append h to history (ordered before next use by B1..B3)
    if (own && t < T_STEPS - 1) hist[t][r] = hv;
  }

  if (own) out[(size_t)b * DH + r] = hv;
}

extern "C" void kernel_launch(void* const* d_in, const int* in_sizes, int n_in,
                              void* d_out, int out_size, void* d_ws, size_t ws_size,
                              hipStream_t stream) {
  const float* z     = (const float*)d_in[0];  // [T,B,DG]
  const float* W_h   = (const float*)d_in[1];  // [DH,DH]
  const float* W_g   = (const float*)d_in[2];  // [DH,DG]
  const float* b_h   = (const float*)d_in[3];  // [DH]
  const float* gamma = (const float*)d_in[4];  // [DH]
  const float* beta  = (const float*)d_in[5];  // [DH]
  float* out = (float*)d_out;                  // [B,DH]

  float* ZG = (float*)d_ws;                                            // 2 MB
  uint4* Wp = (uint4*)((char*)d_ws + (size_t)T_STEPS * BATCH * DH * 4); // 512 KB

  aux_kernel<<<dim3(320), dim3(512), 0, stream>>>(z, W_g, b_h, ZG, W_h, Wp);
  rnn_kernel<<<dim3(BATCH), dim3(1024), 0, stream>>>(Wp, ZG, gamma, beta, out);
}